// Round 18
// baseline (494.800 us; speedup 1.0000x reference)
//
#include <hip/hip_runtime.h>
#include <hip/hip_bf16.h>
#include <hip/hip_fp16.h>

// tanh-RNN + FC on MI355X.
// conv_w -> gemm_xproj (f16 MFMA, 128x128 tiles, packed scan-native xp via LDS
// repack) -> rnn_scan17 (R17 + XOR-swizzled DOUBLE-BUFFERED h -> ONE lgkm-only
// barrier/step; term masks in registers; LDS = 160KB exactly)
// -> gemm_logits (in-place over d_out).

typedef _Float16 half8 __attribute__((ext_vector_type(8)));
typedef _Float16 half4 __attribute__((ext_vector_type(4)));
typedef float f32x4 __attribute__((ext_vector_type(4)));

// ws layout (bytes)
#define XPW_OFF   0UL            // 64MB x_proj f16 (packed scan-native layout)
#define WIH_OFF   67108864UL     // 512KB f16 W_ih
#define FCW_OFF   67633152UL     // 256KB f16 fc_w
#define BIAS_OFF  67895296UL     // 2KB f32 bias2
#define WRESA_OFF 67897344UL     // 384KB AGPR W frags [w(8)][nt(3)][s(16)][lane(64)][8]
#define WRESL_OFF 68290560UL     // 128KB LDS  W frags [w(8)][s(16)][lane(64)][8]

// Column mapping: wave w, frag-lane ln, tile nt -> col = w*64 + ln*4 + nt.
// nt = 0..2 live in AGPRs, nt = 3 in the LDS W tile.
// hb layout (XOR-swizzled, stride 128, double-buffered):
//   elem (k,row) in buf p at p*8192 + (k>>3)*128 + ((row ^ ((k>>3)&7))<<3) + (k&7)

// LDS-ordering-only barrier: waits DS ops, NOT outstanding global (vmcnt).
#define LDS_BARRIER()                                              \
    do {                                                           \
        __builtin_amdgcn_sched_barrier(0);                         \
        asm volatile("s_waitcnt lgkmcnt(0)" ::: "memory");         \
        __builtin_amdgcn_s_barrier();                              \
        __builtin_amdgcn_sched_barrier(0);                         \
    } while (0)

// ---------------------------------------------------------------------------
// conv_w: f16 W_ih, fc_w; bias2 = b_ih + b_hh; W_hh -> B-frag layouts with the
// interleaved column map: frag (w,nt,s) lane l elem i =
//   Whh[w*64 + (l&15)*4 + nt][s*32 + (l>>4)*8 + i]
// ---------------------------------------------------------------------------
__global__ void conv_w(const float* __restrict__ Wih, const float* __restrict__ Whh,
                       const float* __restrict__ fcw, const float* __restrict__ bih,
                       const float* __restrict__ bhh,
                       _Float16* __restrict__ wih_h, _Float16* __restrict__ fcw_h,
                       float* __restrict__ bias2,
                       _Float16* __restrict__ wresA, _Float16* __restrict__ wresL) {
    int idx = blockIdx.x * 256 + threadIdx.x;
    if (idx < 262144) wih_h[idx] = (_Float16)Wih[idx];
    if (idx < 196608) {   // wresA: [w(8)][nt(3)][s(16)][lane][8]
        const int i = idx & 7, l = (idx >> 3) & 63, s = (idx >> 9) & 15;
        const int rest = idx >> 13;              // w*3 + nt, 0..23
        const int w = rest / 3, nt = rest % 3;
        const int row = w * 64 + (l & 15) * 4 + nt;
        wresA[idx] = (_Float16)Whh[(size_t)row * 512 + s * 32 + (l >> 4) * 8 + i];
    }
    if (idx < 65536) {    // wresL: [w(8)][s(16)][lane][8], nt = 3
        const int i = idx & 7, l = (idx >> 3) & 63, s = (idx >> 9) & 15, w = idx >> 13;
        const int row = w * 64 + (l & 15) * 4 + 3;
        wresL[idx] = (_Float16)Whh[(size_t)row * 512 + s * 32 + (l >> 4) * 8 + i];
    }
    if (idx < 131072) fcw_h[idx] = (_Float16)fcw[idx];
    if (idx < 512) bias2[idx] = bih[idx] + bhh[idx];
}

// ---------------------------------------------------------------------------
// K1: x_proj = states @ W_ih^T + bias2, packed scan-native output.
// 128x128 tiles: 2048 blocks = 512 b x 4 col-blocks; 256 thr (2x2 waves).
// Epilogue repacks through a 32KB LDS tile into the scan-packed layout.
// ---------------------------------------------------------------------------
__global__ __launch_bounds__(256) void gemm_xproj(const float* __restrict__ A,
                                                  const _Float16* __restrict__ Bw,
                                                  const float* __restrict__ bias2,
                                                  _Float16* __restrict__ out) {
    __shared__ _Float16 As[128 * 32];
    __shared__ _Float16 Bs[128 * 32];
    __shared__ _Float16 ep[128 * 128];   // epilogue repack tile (32KB)
    const int tid = threadIdx.x;
    const int s_ = blockIdx.x;
    const int z = s_ & 7, k_ = s_ >> 3;          // 2048 blocks
    const int gid = z * 256 + k_;
    const int b = gid >> 2;              // batch
    const int cb2 = gid & 3;             // 128-col block
    const int lane = tid & 63, w1 = tid >> 6;
    const int wr = (w1 >> 1) * 64, wc = (w1 & 1) * 64;
    const int ln = lane & 15, kg = lane >> 4;

    f32x4 acc[4][4];
#pragma unroll
    for (int m = 0; m < 4; m++)
#pragma unroll
        for (int n = 0; n < 4; n++) acc[m][n] = (f32x4)0.0f;

    const int sr = tid >> 1, sc = (tid & 1) * 16;      // A/B staging: 128 x 32
    const int brow = cb2 * 128 + sr;

    for (int k0 = 0; k0 < 512; k0 += 32) {
        {
            const float* ga = A + (size_t)(b * 128 + sr) * 512 + k0 + sc;
            float4 f0 = *(const float4*)(ga + 0);
            float4 f1 = *(const float4*)(ga + 4);
            float4 f2 = *(const float4*)(ga + 8);
            float4 f3 = *(const float4*)(ga + 12);
            half8 h0, h1;
            h0[0] = (_Float16)f0.x; h0[1] = (_Float16)f0.y; h0[2] = (_Float16)f0.z; h0[3] = (_Float16)f0.w;
            h0[4] = (_Float16)f1.x; h0[5] = (_Float16)f1.y; h0[6] = (_Float16)f1.z; h0[7] = (_Float16)f1.w;
            h1[0] = (_Float16)f2.x; h1[1] = (_Float16)f2.y; h1[2] = (_Float16)f2.z; h1[3] = (_Float16)f2.w;
            h1[4] = (_Float16)f3.x; h1[5] = (_Float16)f3.y; h1[6] = (_Float16)f3.z; h1[7] = (_Float16)f3.w;
            *(half8*)&As[sr * 32 + sc] = h0;
            *(half8*)&As[sr * 32 + sc + 8] = h1;
        }
        {
            const _Float16* gb = Bw + (size_t)brow * 512 + k0 + sc;
            *(half8*)&Bs[sr * 32 + sc] = *(const half8*)(gb);
            *(half8*)&Bs[sr * 32 + sc + 8] = *(const half8*)(gb + 8);
        }
        __syncthreads();
        half8 af[4], bf[4];
#pragma unroll
        for (int m = 0; m < 4; m++) af[m] = *(const half8*)&As[(wr + m * 16 + ln) * 32 + kg * 8];
#pragma unroll
        for (int n = 0; n < 4; n++) bf[n] = *(const half8*)&Bs[(wc + n * 16 + ln) * 32 + kg * 8];
#pragma unroll
        for (int m = 0; m < 4; m++)
#pragma unroll
            for (int n = 0; n < 4; n++)
                acc[m][n] = __builtin_amdgcn_mfma_f32_16x16x32_f16(af[m], bf[n], acc[m][n], 0, 0, 0);
        __syncthreads();
    }
    // ---- epilogue: bias; stage t x col_local into ep; repack to packed layout ----
    float bv[4];
#pragma unroll
    for (int n = 0; n < 4; n++) bv[n] = bias2[cb2 * 128 + wc + n * 16 + ln];
#pragma unroll
    for (int m = 0; m < 4; m++)
#pragma unroll
        for (int q = 0; q < 4; q++) {
            const int t = wr + m * 16 + kg * 4 + q;
#pragma unroll
            for (int n = 0; n < 4; n++)
                ep[t * 128 + wc + n * 16 + ln] = (_Float16)(acc[m][n][q] + bv[n]);
        }
    __syncthreads();
    const int bg = b >> 4, kgs = (b >> 2) & 3, qs = b & 3;
    const size_t obase = (size_t)(bg * 128) * 8192 + (size_t)(cb2 * 2 * 64 + kgs * 16) * 16 + qs * 4;
#pragma unroll
    for (int j = 0; j < 16; j++) {
        const int wid = j * 256 + tid;       // 0..4095 = t2*32 + slb
        const int t2 = wid >> 5, slb = wid & 31;
        const half4 v = *(const half4*)&ep[t2 * 128 + slb * 4];
        *(half4*)&out[obase + (size_t)t2 * 8192 + (slb >> 4) * 1024 + (slb & 15) * 16] = v;
    }
}

// ---------------------------------------------------------------------------
// Scan v17: 32 blocks x 512 thr (8 waves, 2/SIMD). Wave w owns cols
// [w*64, w*64+64) with col = w*64 + ln*4 + nt; nt=0..2 as 48 AGPR frags
// (192 regs, "+a"-pinned), nt=3 from the 128KB LDS W tile. h XOR-swizzled,
// DOUBLE-BUFFERED (2 x 16KB): step t reads buf[t&1], writes buf[(t&1)^1] ->
// ONE lgkm-only barrier/step. term masks in registers. LDS = 160KB exactly.
// ---------------------------------------------------------------------------
__global__ __launch_bounds__(512, 2) void rnn_scan17(
    const _Float16* __restrict__ xps,     // packed scan-native x_proj
    const _Float16* __restrict__ wresA,   // AGPR frags
    const _Float16* __restrict__ wresL,   // LDS frags
    const int* __restrict__ term,         // [512][128] int32
    const float* __restrict__ h0,         // [512][512] f32
    float* dout) {
    __shared__ __align__(16) _Float16 hb[16384];     // h, swizzled, dbuf (32KB)
    __shared__ __align__(16) _Float16 wl[65536];     // W nt=3 tiles (128KB)
    const int tid = threadIdx.x;
    const int bg = blockIdx.x;
    const int R0 = bg * 16;
    const int lane = tid & 63, w = tid >> 6;
    const int ln = lane & 15, kg = lane >> 4;
    _Float16* rnn = (_Float16*)dout;

    // ---- 48 AGPR frags (192 AGPRs); per-wave stride 48*512 = 24576 ----
    half8 wf[48];
    {
        const _Float16* wp = wresA + (size_t)w * 24576 + lane * 8;
#pragma unroll
        for (int f = 0; f < 48; f++) wf[f] = *(const half8*)(wp + (size_t)f * 512);
    }
#pragma unroll
    for (int f = 0; f < 48; f++) asm volatile("" : "+a"(wf[f]));

    // ---- termination masks: stage through wl, then hold in 16 registers ----
    unsigned tmr0[4], tmr1[4], tmr2[4], tmr3[4];
    {
        unsigned* tw = (unsigned*)wl;
        if (tid < 64) {
            const int r = tid >> 2, word = tid & 3;
            unsigned m = 0;
            for (int b2 = 0; b2 < 32; b2++)
                m |= (term[(R0 + r) * 128 + word * 32 + b2] ? 1u : 0u) << b2;
            tw[tid] = m;
        }
        __syncthreads();
#pragma unroll
        for (int q = 0; q < 4; q++) {
            const int r4 = (kg * 4 + q) * 4;
            tmr0[q] = tw[r4 + 0];
            tmr1[q] = tw[r4 + 1];
            tmr2[q] = tw[r4 + 2];
            tmr3[q] = tw[r4 + 3];
        }
        __syncthreads();
    }

    // ---- stage LDS W tile (128KB linear, overwrites term staging) ----
    for (int u = 0; u < 16; u++) {
        const int o = (u * 512 + tid) * 8;
        *(half8*)&wl[o] = *(const half8*)(wresL + o);
    }
    // ---- h0 -> hb buf 0 (f32 -> f16, XOR-swizzled) ----
    {
        const int r = tid >> 5, c0 = (tid & 31) * 16;
        const float* gh = h0 + (size_t)(R0 + r) * 512 + c0;
        half8 v0, v1;
#pragma unroll
        for (int i = 0; i < 8; i++) { v0[i] = (_Float16)gh[i]; v1[i] = (_Float16)gh[8 + i]; }
        const int kb = c0 >> 3;
        *(half8*)&hb[kb * 128 + ((r ^ (kb & 7)) << 3)] = v0;
        *(half8*)&hb[(kb + 1) * 128 + ((r ^ ((kb + 1) & 7)) << 3)] = v1;
    }
    __syncthreads();   // startup barrier (full drain fine, once)

    const _Float16* xpt = xps + (size_t)(bg * 128) * 8192 + tid * 16;
    const _Float16* bl = &wl[(size_t)w * 8192];
    const int cb = w * 64 + ln * 4;                  // thread's 4-col base
    const int kbw = cb >> 3;                         // write kblock
    // a-frag read bases: addr(s) = s*512 + (s odd ? A1 : A0)
    const int A0 = kg * 128 + ((ln ^ kg) << 3);
    const int A1 = kg * 128 + ((ln ^ (kg + 4)) << 3);
    // write offsets per q (swizzled row)
    int woff[4];
#pragma unroll
    for (int q = 0; q < 4; q++)
        woff[q] = kbw * 128 + ((((kg * 4 + q) ^ (kbw & 7))) << 3) + (cb & 7);
    unsigned tmask[4];

#pragma unroll 1
    for (int t = 0; t < 128; ++t) {
        if ((t & 31) == 0) {
            const int sel = t >> 5;
#pragma unroll
            for (int q = 0; q < 4; q++)
                tmask[q] = sel == 0 ? tmr0[q] : sel == 1 ? tmr1[q] : sel == 2 ? tmr2[q] : tmr3[q];
        }
        // xp(t): 32B/thread, [q][nt] packed; lands during the MFMA phase
        const half8 xv0 = *(const half8*)(xpt);
        const half8 xv1 = *(const half8*)(xpt + 8);
        xpt += 8192;

        const _Float16* hr = hb + (t & 1) * 8192;    // read buf: h(t)
        _Float16* hw = hb + ((t & 1) ^ 1) * 8192;    // write buf: h(t+1)

        f32x4 acc[4];
#pragma unroll
        for (int n = 0; n < 4; n++) acc[n] = (f32x4)0.0f;

#pragma unroll
        for (int s = 0; s < 16; s++) {
            const half8 a = *(const half8*)&hr[s * 512 + ((s & 1) ? A1 : A0)];
            acc[0] = __builtin_amdgcn_mfma_f32_16x16x32_f16(a, wf[s],      acc[0], 0, 0, 0);
            acc[1] = __builtin_amdgcn_mfma_f32_16x16x32_f16(a, wf[16 + s], acc[1], 0, 0, 0);
            acc[2] = __builtin_amdgcn_mfma_f32_16x16x32_f16(a, wf[32 + s], acc[2], 0, 0, 0);
            const half8 b4 = *(const half8*)(bl + s * 512 + lane * 8);
            acc[3] = __builtin_amdgcn_mfma_f32_16x16x32_f16(a, b4, acc[3], 0, 0, 0);
        }

        // ---- tanh (rcp); masked h(t+1) -> hw (other buffer, no barrier first) ----
        half4 hh4[4];
#pragma unroll
        for (int q = 0; q < 4; q++) {
            const bool dead = (tmask[q] >> (t & 31)) & 1;
            half4 v;
#pragma unroll
            for (int nt = 0; nt < 4; nt++) {
                const int u = q * 4 + nt;
                const float xval = (float)(u < 8 ? xv0[u] : xv1[u - 8]);
                const float pre = acc[nt][q] + xval;
                const float e = __expf(2.0f * pre);
                v[nt] = (_Float16)(1.0f - 2.0f * __builtin_amdgcn_rcpf(e + 1.0f));
            }
            hh4[q] = v;
            half4 mv = v;
            if (dead) { mv[0] = (_Float16)0; mv[1] = (_Float16)0; mv[2] = (_Float16)0; mv[3] = (_Float16)0; }
            *(half4*)&hw[woff[q]] = mv;
        }

        // rnn_out stores: 4 x 8B (128B segments per 16 lanes), no drain needed
#pragma unroll
        for (int q = 0; q < 4; q++)
            *(half4*)&rnn[((size_t)(R0 + kg * 4 + q) * 128 + t) * 512 + cb] = hh4[q];

        LDS_BARRIER();     // the ONLY barrier: reads[t] and writes[t+1] complete
    }

    // ---- h_final (masked h(128), in buf 0) -> f32 at d_out + 65536*256 ----
    {
        const int r = tid >> 5, c0 = (tid & 31) * 16;
        const int kb = c0 >> 3;
        half8 v0 = *(const half8*)&hb[kb * 128 + ((r ^ (kb & 7)) << 3)];
        half8 v1 = *(const half8*)&hb[(kb + 1) * 128 + ((r ^ ((kb + 1) & 7)) << 3)];
        float* gf = dout + (size_t)65536 * 256 + (size_t)(R0 + r) * 512 + c0;
#pragma unroll
        for (int i = 0; i < 8; i++) { gf[i] = (float)v0[i]; gf[8 + i] = (float)v1[i]; }
    }
}

// ---------------------------------------------------------------------------
// K3: logits[65536,256] (f32) = rnn_out(f16, in d_out) @ fc_w^T + fc_b
// ---------------------------------------------------------------------------
__global__ __launch_bounds__(512) void gemm_logits(const _Float16* Arnn,
                                                   const _Float16* __restrict__ Bw,
                                                   const float* __restrict__ biasv,
                                                   float* out) {
    __shared__ _Float16 As[128 * 32];
    __shared__ _Float16 Bs[256 * 32];
    const int tid = threadIdx.x;
    const int m0 = blockIdx.x * 128;
    const int lane = tid & 63, w = tid >> 6;
    const int wr = (w >> 2) * 64, wc = (w & 3) * 64;
    const int ln = lane & 15, kg = lane >> 4;

    f32x4 acc[4][4];
#pragma unroll
    for (int m = 0; m < 4; m++)
#pragma unroll
        for (int n = 0; n < 4; n++) acc[m][n] = (f32x4)0.0f;

    const int ar = tid >> 2, ac = (tid & 3) * 8;
    const int br = tid >> 1, bc = (tid & 1) * 16;

    for (int k0 = 0; k0 < 512; k0 += 32) {
        *(half8*)&As[ar * 32 + ac] = *(const half8*)(Arnn + (size_t)(m0 + ar) * 512 + k0 + ac);
        {
            const _Float16* gb = Bw + (size_t)br * 512 + k0 + bc;
            *(half8*)&Bs[br * 32 + bc] = *(const half8*)(gb);
            *(half8*)&Bs[br * 32 + bc + 8] = *(const half8*)(gb + 8);
        }
        __syncthreads();
        half8 af[4], bf[4];
#pragma unroll
        for (int m = 0; m < 4; m++) af[m] = *(const half8*)&As[(wr + m * 16 + ln) * 32 + kg * 8];
#pragma unroll
        for (int n = 0; n < 4; n++) bf[n] = *(const half8*)&Bs[(wc + n * 16 + ln) * 32 + kg * 8];
#pragma unroll
        for (int m = 0; m < 4; m++)
#pragma unroll
            for (int n = 0; n < 4; n++)
                acc[m][n] = __builtin_amdgcn_mfma_f32_16x16x32_f16(af[m], bf[n], acc[m][n], 0, 0, 0);
        __syncthreads();
    }
#pragma unroll
    for (int m = 0; m < 4; m++)
#pragma unroll
        for (int n = 0; n < 4; n++) {
            const int col = wc + n * 16 + ln;
            const float bv = biasv[col];
#pragma unroll
            for (int q = 0; q < 4; q++) {
                const int row = m0 + wr + m * 16 + kg * 4 + q;
                out[(size_t)row * 256 + col] = acc[m][n][q] + bv;
            }
        }
}

// ---------------------------------------------------------------------------
extern "C" void kernel_launch(void* const* d_in, const int* in_sizes, int n_in,
                              void* d_out, int out_size, void* d_ws, size_t ws_size,
                              hipStream_t stream) {
    const float* states = (const float*)d_in[0];
    const int*   term   = (const int*)d_in[1];
    const float* h0     = (const float*)d_in[2];
    const float* Wih    = (const float*)d_in[3];
    const float* Whh    = (const float*)d_in[4];
    const float* bih    = (const float*)d_in[5];
    const float* bhh    = (const float*)d_in[6];
    const float* fcw    = (const float*)d_in[7];
    const float* fcb    = (const float*)d_in[8];

    char* ws = (char*)d_ws;
    _Float16* xpw   = (_Float16*)(ws + XPW_OFF);
    _Float16* wih_h = (_Float16*)(ws + WIH_OFF);
    _Float16* fcw_h = (_Float16*)(ws + FCW_OFF);
    float*    bias2 = (float*)(ws + BIAS_OFF);
    _Float16* wresA = (_Float16*)(ws + WRESA_OFF);
    _Float16* wresL = (_Float16*)(ws + WRESL_OFF);

    conv_w<<<1024, 256, 0, stream>>>(Wih, Whh, fcw, bih, bhh, wih_h, fcw_h, bias2, wresA, wresL);
    gemm_xproj<<<2048, 256, 0, stream>>>(states, wih_h, bias2, xpw);
    rnn_scan17<<<32, 512, 0, stream>>>(xpw, wresA, wresL, term, h0, (float*)d_out);
    gemm_logits<<<512, 512, 0, stream>>>((const _Float16*)d_out, fcw_h, fcb, (float*)d_out);
}

// Round 19
// 462.633 us; speedup vs baseline: 1.0695x; 1.0695x over previous
//
#include <hip/hip_runtime.h>
#include <hip/hip_bf16.h>
#include <hip/hip_fp16.h>

// tanh-RNN + FC on MI355X.
// conv_w -> gemm_xproj (f16 MFMA, 128x128 tiles, packed scan-native xp via LDS
// repack) -> rnn_scan18 (R17's 2-barrier single-buffer structure + R18's
// conflict-free XOR-swizzled hb) -> gemm_logits (in-place over d_out).

typedef _Float16 half8 __attribute__((ext_vector_type(8)));
typedef _Float16 half4 __attribute__((ext_vector_type(4)));
typedef float f32x4 __attribute__((ext_vector_type(4)));

// ws layout (bytes)
#define XPW_OFF   0UL            // 64MB x_proj f16 (packed scan-native layout)
#define WIH_OFF   67108864UL     // 512KB f16 W_ih
#define FCW_OFF   67633152UL     // 256KB f16 fc_w
#define BIAS_OFF  67895296UL     // 2KB f32 bias2
#define WRESA_OFF 67897344UL     // 384KB AGPR W frags [w(8)][nt(3)][s(16)][lane(64)][8]
#define WRESL_OFF 68290560UL     // 128KB LDS  W frags [w(8)][s(16)][lane(64)][8]

// Column mapping: wave w, frag-lane ln, tile nt -> col = w*64 + ln*4 + nt.
// nt = 0..2 live in AGPRs, nt = 3 in the LDS W tile.
// hb layout (XOR-swizzled, single buffer):
//   elem (k,row) at (k>>3)*128 + ((row ^ ((k>>3)&7))<<3) + (k&7)

// LDS-ordering-only barrier: waits DS ops, NOT outstanding global (vmcnt).
#define LDS_BARRIER()                                              \
    do {                                                           \
        __builtin_amdgcn_sched_barrier(0);                         \
        asm volatile("s_waitcnt lgkmcnt(0)" ::: "memory");         \
        __builtin_amdgcn_s_barrier();                              \
        __builtin_amdgcn_sched_barrier(0);                         \
    } while (0)

// ---------------------------------------------------------------------------
// conv_w: f16 W_ih, fc_w; bias2 = b_ih + b_hh; W_hh -> B-frag layouts with the
// interleaved column map: frag (w,nt,s) lane l elem i =
//   Whh[w*64 + (l&15)*4 + nt][s*32 + (l>>4)*8 + i]
// ---------------------------------------------------------------------------
__global__ void conv_w(const float* __restrict__ Wih, const float* __restrict__ Whh,
                       const float* __restrict__ fcw, const float* __restrict__ bih,
                       const float* __restrict__ bhh,
                       _Float16* __restrict__ wih_h, _Float16* __restrict__ fcw_h,
                       float* __restrict__ bias2,
                       _Float16* __restrict__ wresA, _Float16* __restrict__ wresL) {
    int idx = blockIdx.x * 256 + threadIdx.x;
    if (idx < 262144) wih_h[idx] = (_Float16)Wih[idx];
    if (idx < 196608) {   // wresA: [w(8)][nt(3)][s(16)][lane][8]
        const int i = idx & 7, l = (idx >> 3) & 63, s = (idx >> 9) & 15;
        const int rest = idx >> 13;              // w*3 + nt, 0..23
        const int w = rest / 3, nt = rest % 3;
        const int row = w * 64 + (l & 15) * 4 + nt;
        wresA[idx] = (_Float16)Whh[(size_t)row * 512 + s * 32 + (l >> 4) * 8 + i];
    }
    if (idx < 65536) {    // wresL: [w(8)][s(16)][lane][8], nt = 3
        const int i = idx & 7, l = (idx >> 3) & 63, s = (idx >> 9) & 15, w = idx >> 13;
        const int row = w * 64 + (l & 15) * 4 + 3;
        wresL[idx] = (_Float16)Whh[(size_t)row * 512 + s * 32 + (l >> 4) * 8 + i];
    }
    if (idx < 131072) fcw_h[idx] = (_Float16)fcw[idx];
    if (idx < 512) bias2[idx] = bih[idx] + bhh[idx];
}

// ---------------------------------------------------------------------------
// K1: x_proj = states @ W_ih^T + bias2, packed scan-native output.
// 128x128 tiles: 2048 blocks = 512 b x 4 col-blocks; 256 thr (2x2 waves).
// Epilogue repacks through a 32KB LDS tile into the scan-packed layout.
// ---------------------------------------------------------------------------
__global__ __launch_bounds__(256) void gemm_xproj(const float* __restrict__ A,
                                                  const _Float16* __restrict__ Bw,
                                                  const float* __restrict__ bias2,
                                                  _Float16* __restrict__ out) {
    __shared__ _Float16 As[128 * 32];
    __shared__ _Float16 Bs[128 * 32];
    __shared__ _Float16 ep[128 * 128];   // epilogue repack tile (32KB)
    const int tid = threadIdx.x;
    const int s_ = blockIdx.x;
    const int z = s_ & 7, k_ = s_ >> 3;          // 2048 blocks
    const int gid = z * 256 + k_;
    const int b = gid >> 2;              // batch
    const int cb2 = gid & 3;             // 128-col block
    const int lane = tid & 63, w1 = tid >> 6;
    const int wr = (w1 >> 1) * 64, wc = (w1 & 1) * 64;
    const int ln = lane & 15, kg = lane >> 4;

    f32x4 acc[4][4];
#pragma unroll
    for (int m = 0; m < 4; m++)
#pragma unroll
        for (int n = 0; n < 4; n++) acc[m][n] = (f32x4)0.0f;

    const int sr = tid >> 1, sc = (tid & 1) * 16;      // A/B staging: 128 x 32
    const int brow = cb2 * 128 + sr;

    for (int k0 = 0; k0 < 512; k0 += 32) {
        {
            const float* ga = A + (size_t)(b * 128 + sr) * 512 + k0 + sc;
            float4 f0 = *(const float4*)(ga + 0);
            float4 f1 = *(const float4*)(ga + 4);
            float4 f2 = *(const float4*)(ga + 8);
            float4 f3 = *(const float4*)(ga + 12);
            half8 h0, h1;
            h0[0] = (_Float16)f0.x; h0[1] = (_Float16)f0.y; h0[2] = (_Float16)f0.z; h0[3] = (_Float16)f0.w;
            h0[4] = (_Float16)f1.x; h0[5] = (_Float16)f1.y; h0[6] = (_Float16)f1.z; h0[7] = (_Float16)f1.w;
            h1[0] = (_Float16)f2.x; h1[1] = (_Float16)f2.y; h1[2] = (_Float16)f2.z; h1[3] = (_Float16)f2.w;
            h1[4] = (_Float16)f3.x; h1[5] = (_Float16)f3.y; h1[6] = (_Float16)f3.z; h1[7] = (_Float16)f3.w;
            *(half8*)&As[sr * 32 + sc] = h0;
            *(half8*)&As[sr * 32 + sc + 8] = h1;
        }
        {
            const _Float16* gb = Bw + (size_t)brow * 512 + k0 + sc;
            *(half8*)&Bs[sr * 32 + sc] = *(const half8*)(gb);
            *(half8*)&Bs[sr * 32 + sc + 8] = *(const half8*)(gb + 8);
        }
        __syncthreads();
        half8 af[4], bf[4];
#pragma unroll
        for (int m = 0; m < 4; m++) af[m] = *(const half8*)&As[(wr + m * 16 + ln) * 32 + kg * 8];
#pragma unroll
        for (int n = 0; n < 4; n++) bf[n] = *(const half8*)&Bs[(wc + n * 16 + ln) * 32 + kg * 8];
#pragma unroll
        for (int m = 0; m < 4; m++)
#pragma unroll
            for (int n = 0; n < 4; n++)
                acc[m][n] = __builtin_amdgcn_mfma_f32_16x16x32_f16(af[m], bf[n], acc[m][n], 0, 0, 0);
        __syncthreads();
    }
    // ---- epilogue: bias; stage t x col_local into ep; repack to packed layout ----
    float bv[4];
#pragma unroll
    for (int n = 0; n < 4; n++) bv[n] = bias2[cb2 * 128 + wc + n * 16 + ln];
#pragma unroll
    for (int m = 0; m < 4; m++)
#pragma unroll
        for (int q = 0; q < 4; q++) {
            const int t = wr + m * 16 + kg * 4 + q;
#pragma unroll
            for (int n = 0; n < 4; n++)
                ep[t * 128 + wc + n * 16 + ln] = (_Float16)(acc[m][n][q] + bv[n]);
        }
    __syncthreads();
    const int bg = b >> 4, kgs = (b >> 2) & 3, qs = b & 3;
    const size_t obase = (size_t)(bg * 128) * 8192 + (size_t)(cb2 * 2 * 64 + kgs * 16) * 16 + qs * 4;
#pragma unroll
    for (int j = 0; j < 16; j++) {
        const int wid = j * 256 + tid;       // 0..4095 = t2*32 + slb
        const int t2 = wid >> 5, slb = wid & 31;
        const half4 v = *(const half4*)&ep[t2 * 128 + slb * 4];
        *(half4*)&out[obase + (size_t)t2 * 8192 + (slb >> 4) * 1024 + (slb & 15) * 16] = v;
    }
}

// ---------------------------------------------------------------------------
// Scan v18: 32 blocks x 512 thr (8 waves, 2/SIMD). Wave w owns cols
// [w*64, w*64+64) with col = w*64 + ln*4 + nt; nt=0..2 as 48 AGPR frags
// (192 regs, "+a"-pinned), nt=3 from the 128KB LDS W tile. h single-buffered
// XOR-swizzled (conflict-free reads AND writes); 2 lgkm-only barriers/step;
// rnn stores after barrier2 (drain overlaps next MFMA phase).
// ---------------------------------------------------------------------------
__global__ __launch_bounds__(512, 2) void rnn_scan18(
    const _Float16* __restrict__ xps,     // packed scan-native x_proj
    const _Float16* __restrict__ wresA,   // AGPR frags
    const _Float16* __restrict__ wresL,   // LDS frags
    const int* __restrict__ term,         // [512][128] int32
    const float* __restrict__ h0,         // [512][512] f32
    float* dout) {
    __shared__ __align__(16) _Float16 hb[8192];      // h, XOR-swizzled (16KB)
    __shared__ __align__(16) _Float16 wl[65536];     // W nt=3 tiles (128KB)
    __shared__ unsigned int term_lds[16][4];
    const int tid = threadIdx.x;
    const int bg = blockIdx.x;
    const int R0 = bg * 16;
    const int lane = tid & 63, w = tid >> 6;
    const int ln = lane & 15, kg = lane >> 4;
    _Float16* rnn = (_Float16*)dout;

    // ---- 48 AGPR frags (192 AGPRs); per-wave stride 48*512 = 24576 ----
    half8 wf[48];
    {
        const _Float16* wp = wresA + (size_t)w * 24576 + lane * 8;
#pragma unroll
        for (int f = 0; f < 48; f++) wf[f] = *(const half8*)(wp + (size_t)f * 512);
    }
#pragma unroll
    for (int f = 0; f < 48; f++) asm volatile("" : "+a"(wf[f]));

    // ---- stage LDS W tile (128KB linear) ----
    for (int u = 0; u < 16; u++) {
        const int o = (u * 512 + tid) * 8;
        *(half8*)&wl[o] = *(const half8*)(wresL + o);
    }
    // ---- h0 -> hb (f32 -> f16, XOR-swizzled) ----
    {
        const int r = tid >> 5, c0 = (tid & 31) * 16;
        const float* gh = h0 + (size_t)(R0 + r) * 512 + c0;
        half8 v0, v1;
#pragma unroll
        for (int i = 0; i < 8; i++) { v0[i] = (_Float16)gh[i]; v1[i] = (_Float16)gh[8 + i]; }
        const int kb = c0 >> 3;
        *(half8*)&hb[kb * 128 + ((r ^ (kb & 7)) << 3)] = v0;
        *(half8*)&hb[(kb + 1) * 128 + ((r ^ ((kb + 1) & 7)) << 3)] = v1;
    }
    // ---- termination bitmasks ----
    if (tid < 64) {
        const int r = tid >> 2, word = tid & 3;
        unsigned int m = 0;
        for (int b2 = 0; b2 < 32; b2++)
            m |= (term[(R0 + r) * 128 + word * 32 + b2] ? 1u : 0u) << b2;
        term_lds[r][word] = m;
    }
    __syncthreads();   // startup barrier: full drain fine (once)

    const _Float16* xpt = xps + (size_t)(bg * 128) * 8192 + tid * 16;
    const _Float16* bl = &wl[(size_t)w * 8192];
    const int cb = w * 64 + ln * 4;                  // thread's 4-col base
    const int kbw = cb >> 3;                         // write kblock
    // a-frag read bases: addr(s) = s*512 + (s odd ? A1 : A0)
    const int A0 = kg * 128 + ((ln ^ kg) << 3);
    const int A1 = kg * 128 + ((ln ^ (kg + 4)) << 3);
    // write offsets per q (swizzled row)
    int woff[4];
#pragma unroll
    for (int q = 0; q < 4; q++)
        woff[q] = kbw * 128 + ((((kg * 4 + q) ^ (kbw & 7))) << 3) + (cb & 7);
    unsigned tmask[4];

#pragma unroll 1
    for (int t = 0; t < 128; ++t) {
        if ((t & 31) == 0) {
#pragma unroll
            for (int q = 0; q < 4; q++) tmask[q] = term_lds[kg * 4 + q][t >> 5];
        }
        // xp(t): 32B/thread, [q][nt] packed; lands during the MFMA phase
        const half8 xv0 = *(const half8*)(xpt);
        const half8 xv1 = *(const half8*)(xpt + 8);
        xpt += 8192;

        f32x4 acc[4];
#pragma unroll
        for (int n = 0; n < 4; n++) acc[n] = (f32x4)0.0f;

#pragma unroll
        for (int s = 0; s < 16; s++) {
            const half8 a = *(const half8*)&hb[s * 512 + ((s & 1) ? A1 : A0)];
            acc[0] = __builtin_amdgcn_mfma_f32_16x16x32_f16(a, wf[s],      acc[0], 0, 0, 0);
            acc[1] = __builtin_amdgcn_mfma_f32_16x16x32_f16(a, wf[16 + s], acc[1], 0, 0, 0);
            acc[2] = __builtin_amdgcn_mfma_f32_16x16x32_f16(a, wf[32 + s], acc[2], 0, 0, 0);
            const half8 b4 = *(const half8*)(bl + s * 512 + lane * 8);
            acc[3] = __builtin_amdgcn_mfma_f32_16x16x32_f16(a, b4, acc[3], 0, 0, 0);
        }
        LDS_BARRIER();     // barrier1: h(t) reads done (lgkm only)

        // ---- tanh (rcp); masked h(t+1) -> hb (swizzled b64); keep half4s ----
        half4 hh4[4];
#pragma unroll
        for (int q = 0; q < 4; q++) {
            const bool dead = (tmask[q] >> (t & 31)) & 1;
            half4 v;
#pragma unroll
            for (int nt = 0; nt < 4; nt++) {
                const int u = q * 4 + nt;
                const float xval = (float)(u < 8 ? xv0[u] : xv1[u - 8]);
                const float pre = acc[nt][q] + xval;
                const float e = __expf(2.0f * pre);
                v[nt] = (_Float16)(1.0f - 2.0f * __builtin_amdgcn_rcpf(e + 1.0f));
            }
            hh4[q] = v;
            half4 mv = v;
            if (dead) { mv[0] = (_Float16)0; mv[1] = (_Float16)0; mv[2] = (_Float16)0; mv[3] = (_Float16)0; }
            *(half4*)&hb[woff[q]] = mv;
        }
        LDS_BARRIER();     // barrier2: h(t+1) visible (lgkm only)

        // ---- rnn_out stores: 4 x 8B (128B segments per 16 lanes), no drain ----
#pragma unroll
        for (int q = 0; q < 4; q++)
            *(half4*)&rnn[((size_t)(R0 + kg * 4 + q) * 128 + t) * 512 + cb] = hh4[q];
    }

    // ---- h_final (masked h(128)) -> f32 at d_out + 65536*256 ----
    {
        const int r = tid >> 5, c0 = (tid & 31) * 16;
        const int kb = c0 >> 3;
        half8 v0 = *(const half8*)&hb[kb * 128 + ((r ^ (kb & 7)) << 3)];
        half8 v1 = *(const half8*)&hb[(kb + 1) * 128 + ((r ^ ((kb + 1) & 7)) << 3)];
        float* gf = dout + (size_t)65536 * 256 + (size_t)(R0 + r) * 512 + c0;
#pragma unroll
        for (int i = 0; i < 8; i++) { gf[i] = (float)v0[i]; gf[8 + i] = (float)v1[i]; }
    }
}

// ---------------------------------------------------------------------------
// K3: logits[65536,256] (f32) = rnn_out(f16, in d_out) @ fc_w^T + fc_b
// ---------------------------------------------------------------------------
__global__ __launch_bounds__(512) void gemm_logits(const _Float16* Arnn,
                                                   const _Float16* __restrict__ Bw,
                                                   const float* __restrict__ biasv,
                                                   float* out) {
    __shared__ _Float16 As[128 * 32];
    __shared__ _Float16 Bs[256 * 32];
    const int tid = threadIdx.x;
    const int m0 = blockIdx.x * 128;
    const int lane = tid & 63, w = tid >> 6;
    const int wr = (w >> 2) * 64, wc = (w & 3) * 64;
    const int ln = lane & 15, kg = lane >> 4;

    f32x4 acc[4][4];
#pragma unroll
    for (int m = 0; m < 4; m++)
#pragma unroll
        for (int n = 0; n < 4; n++) acc[m][n] = (f32x4)0.0f;

    const int ar = tid >> 2, ac = (tid & 3) * 8;
    const int br = tid >> 1, bc = (tid & 1) * 16;

    for (int k0 = 0; k0 < 512; k0 += 32) {
        *(half8*)&As[ar * 32 + ac] = *(const half8*)(Arnn + (size_t)(m0 + ar) * 512 + k0 + ac);
        {
            const _Float16* gb = Bw + (size_t)br * 512 + k0 + bc;
            *(half8*)&Bs[br * 32 + bc] = *(const half8*)(gb);
            *(half8*)&Bs[br * 32 + bc + 8] = *(const half8*)(gb + 8);
        }
        __syncthreads();
        half8 af[4], bf[4];
#pragma unroll
        for (int m = 0; m < 4; m++) af[m] = *(const half8*)&As[(wr + m * 16 + ln) * 32 + kg * 8];
#pragma unroll
        for (int n = 0; n < 4; n++) bf[n] = *(const half8*)&Bs[(wc + n * 16 + ln) * 32 + kg * 8];
#pragma unroll
        for (int m = 0; m < 4; m++)
#pragma unroll
            for (int n = 0; n < 4; n++)
                acc[m][n] = __builtin_amdgcn_mfma_f32_16x16x32_f16(af[m], bf[n], acc[m][n], 0, 0, 0);
        __syncthreads();
    }
#pragma unroll
    for (int m = 0; m < 4; m++)
#pragma unroll
        for (int n = 0; n < 4; n++) {
            const int col = wc + n * 16 + ln;
            const float bv = biasv[col];
#pragma unroll
            for (int q = 0; q < 4; q++) {
                const int row = m0 + wr + m * 16 + kg * 4 + q;
                out[(size_t)row * 256 + col] = acc[m][n][q] + bv;
            }
        }
}

// ---------------------------------------------------------------------------
extern "C" void kernel_launch(void* const* d_in, const int* in_sizes, int n_in,
                              void* d_out, int out_size, void* d_ws, size_t ws_size,
                              hipStream_t stream) {
    const float* states = (const float*)d_in[0];
    const int*   term   = (const int*)d_in[1];
    const float* h0     = (const float*)d_in[2];
    const float* Wih    = (const float*)d_in[3];
    const float* Whh    = (const float*)d_in[4];
    const float* bih    = (const float*)d_in[5];
    const float* bhh    = (const float*)d_in[6];
    const float* fcw    = (const float*)d_in[7];
    const float* fcb    = (const float*)d_in[8];

    char* ws = (char*)d_ws;
    _Float16* xpw   = (_Float16*)(ws + XPW_OFF);
    _Float16* wih_h = (_Float16*)(ws + WIH_OFF);
    _Float16* fcw_h = (_Float16*)(ws + FCW_OFF);
    float*    bias2 = (float*)(ws + BIAS_OFF);
    _Float16* wresA = (_Float16*)(ws + WRESA_OFF);
    _Float16* wresL = (_Float16*)(ws + WRESL_OFF);

    conv_w<<<1024, 256, 0, stream>>>(Wih, Whh, fcw, bih, bhh, wih_h, fcw_h, bias2, wresA, wresL);
    gemm_xproj<<<2048, 256, 0, stream>>>(states, wih_h, bias2, xpw);
    rnn_scan18<<<32, 512, 0, stream>>>(xpw, wresA, wresL, term, h0, (float*)d_out);
    gemm_logits<<<512, 512, 0, stream>>>((const _Float16*)d_out, fcw_h, fcb, (float*)d_out);
}

// Round 20
// 395.934 us; speedup vs baseline: 1.2497x; 1.1685x over previous
//
#include <hip/hip_runtime.h>
#include <hip/hip_bf16.h>
#include <hip/hip_fp16.h>

// tanh-RNN + FC on MI355X.  (R20 = R17 verbatim — the measured optimum.)
// conv_w -> gemm_xproj (f16 MFMA, 128x128 tiles, packed scan-native xp via LDS
// repack) -> rnn_scan16 (2 lgkm-only barriers/step, padded hb stride 136,
// 48 AGPR + 128KB-LDS W residency, packed b64/8B writes) -> gemm_logits.

typedef _Float16 half8 __attribute__((ext_vector_type(8)));
typedef _Float16 half4 __attribute__((ext_vector_type(4)));
typedef float f32x4 __attribute__((ext_vector_type(4)));

// ws layout (bytes)
#define XPW_OFF   0UL            // 64MB x_proj f16 (packed scan-native layout)
#define WIH_OFF   67108864UL     // 512KB f16 W_ih
#define FCW_OFF   67633152UL     // 256KB f16 fc_w
#define BIAS_OFF  67895296UL     // 2KB f32 bias2
#define WRESA_OFF 67897344UL     // 384KB AGPR W frags [w(8)][nt(3)][s(16)][lane(64)][8]
#define WRESL_OFF 68290560UL     // 128KB LDS  W frags [w(8)][s(16)][lane(64)][8]

// Column mapping: wave w, frag-lane ln, tile nt -> col = w*64 + ln*4 + nt.
// nt = 0..2 live in AGPRs, nt = 3 in the LDS W tile.
// hb layout (PADDED): elem (k,row) at (k>>3)*136 + row*8 + (k&7). 64 kblocks.

#define HB_STRIDE 136

// LDS-ordering-only barrier: waits DS ops, NOT outstanding global (vmcnt).
#define LDS_BARRIER()                                              \
    do {                                                           \
        __builtin_amdgcn_sched_barrier(0);                         \
        asm volatile("s_waitcnt lgkmcnt(0)" ::: "memory");         \
        __builtin_amdgcn_s_barrier();                              \
        __builtin_amdgcn_sched_barrier(0);                         \
    } while (0)

// ---------------------------------------------------------------------------
// conv_w: f16 W_ih, fc_w; bias2 = b_ih + b_hh; W_hh -> B-frag layouts with the
// interleaved column map: frag (w,nt,s) lane l elem i =
//   Whh[w*64 + (l&15)*4 + nt][s*32 + (l>>4)*8 + i]
// ---------------------------------------------------------------------------
__global__ void conv_w(const float* __restrict__ Wih, const float* __restrict__ Whh,
                       const float* __restrict__ fcw, const float* __restrict__ bih,
                       const float* __restrict__ bhh,
                       _Float16* __restrict__ wih_h, _Float16* __restrict__ fcw_h,
                       float* __restrict__ bias2,
                       _Float16* __restrict__ wresA, _Float16* __restrict__ wresL) {
    int idx = blockIdx.x * 256 + threadIdx.x;
    if (idx < 262144) wih_h[idx] = (_Float16)Wih[idx];
    if (idx < 196608) {   // wresA: [w(8)][nt(3)][s(16)][lane][8]
        const int i = idx & 7, l = (idx >> 3) & 63, s = (idx >> 9) & 15;
        const int rest = idx >> 13;              // w*3 + nt, 0..23
        const int w = rest / 3, nt = rest % 3;
        const int row = w * 64 + (l & 15) * 4 + nt;
        wresA[idx] = (_Float16)Whh[(size_t)row * 512 + s * 32 + (l >> 4) * 8 + i];
    }
    if (idx < 65536) {    // wresL: [w(8)][s(16)][lane][8], nt = 3
        const int i = idx & 7, l = (idx >> 3) & 63, s = (idx >> 9) & 15, w = idx >> 13;
        const int row = w * 64 + (l & 15) * 4 + 3;
        wresL[idx] = (_Float16)Whh[(size_t)row * 512 + s * 32 + (l >> 4) * 8 + i];
    }
    if (idx < 131072) fcw_h[idx] = (_Float16)fcw[idx];
    if (idx < 512) bias2[idx] = bih[idx] + bhh[idx];
}

// ---------------------------------------------------------------------------
// K1: x_proj = states @ W_ih^T + bias2, packed scan-native output.
// 128x128 tiles: 2048 blocks = 512 b x 4 col-blocks; 256 thr (2x2 waves).
// XCD-grouped: gid = z*256 + k_ -> batches [z*32,(z+1)*32) per XCD (A reuse).
// Epilogue repacks through a 32KB LDS tile into the scan-packed layout:
//   dst(b,t,col) = (bg*128+t)*8192 + (wsp*64 + kgs*16 + sln)*16 + qs*4 + snt
//   wsp = col>>6, sln = (col>>2)&15, snt = col&3; kgs=(b>>2)&3, qs=b&3.
// ---------------------------------------------------------------------------
__global__ __launch_bounds__(256) void gemm_xproj(const float* __restrict__ A,
                                                  const _Float16* __restrict__ Bw,
                                                  const float* __restrict__ bias2,
                                                  _Float16* __restrict__ out) {
    __shared__ _Float16 As[128 * 32];
    __shared__ _Float16 Bs[128 * 32];
    __shared__ _Float16 ep[128 * 128];   // epilogue repack tile (32KB)
    const int tid = threadIdx.x;
    const int s_ = blockIdx.x;
    const int z = s_ & 7, k_ = s_ >> 3;          // 2048 blocks
    const int gid = z * 256 + k_;
    const int b = gid >> 2;              // batch
    const int cb2 = gid & 3;             // 128-col block
    const int lane = tid & 63, w1 = tid >> 6;
    const int wr = (w1 >> 1) * 64, wc = (w1 & 1) * 64;
    const int ln = lane & 15, kg = lane >> 4;

    f32x4 acc[4][4];
#pragma unroll
    for (int m = 0; m < 4; m++)
#pragma unroll
        for (int n = 0; n < 4; n++) acc[m][n] = (f32x4)0.0f;

    const int sr = tid >> 1, sc = (tid & 1) * 16;      // A/B staging: 128 x 32
    const int brow = cb2 * 128 + sr;

    for (int k0 = 0; k0 < 512; k0 += 32) {
        {
            const float* ga = A + (size_t)(b * 128 + sr) * 512 + k0 + sc;
            float4 f0 = *(const float4*)(ga + 0);
            float4 f1 = *(const float4*)(ga + 4);
            float4 f2 = *(const float4*)(ga + 8);
            float4 f3 = *(const float4*)(ga + 12);
            half8 h0, h1;
            h0[0] = (_Float16)f0.x; h0[1] = (_Float16)f0.y; h0[2] = (_Float16)f0.z; h0[3] = (_Float16)f0.w;
            h0[4] = (_Float16)f1.x; h0[5] = (_Float16)f1.y; h0[6] = (_Float16)f1.z; h0[7] = (_Float16)f1.w;
            h1[0] = (_Float16)f2.x; h1[1] = (_Float16)f2.y; h1[2] = (_Float16)f2.z; h1[3] = (_Float16)f2.w;
            h1[4] = (_Float16)f3.x; h1[5] = (_Float16)f3.y; h1[6] = (_Float16)f3.z; h1[7] = (_Float16)f3.w;
            *(half8*)&As[sr * 32 + sc] = h0;
            *(half8*)&As[sr * 32 + sc + 8] = h1;
        }
        {
            const _Float16* gb = Bw + (size_t)brow * 512 + k0 + sc;
            *(half8*)&Bs[sr * 32 + sc] = *(const half8*)(gb);
            *(half8*)&Bs[sr * 32 + sc + 8] = *(const half8*)(gb + 8);
        }
        __syncthreads();
        half8 af[4], bf[4];
#pragma unroll
        for (int m = 0; m < 4; m++) af[m] = *(const half8*)&As[(wr + m * 16 + ln) * 32 + kg * 8];
#pragma unroll
        for (int n = 0; n < 4; n++) bf[n] = *(const half8*)&Bs[(wc + n * 16 + ln) * 32 + kg * 8];
#pragma unroll
        for (int m = 0; m < 4; m++)
#pragma unroll
            for (int n = 0; n < 4; n++)
                acc[m][n] = __builtin_amdgcn_mfma_f32_16x16x32_f16(af[m], bf[n], acc[m][n], 0, 0, 0);
        __syncthreads();
    }
    // ---- epilogue: bias; stage t x col_local into ep; repack to packed layout ----
    float bv[4];
#pragma unroll
    for (int n = 0; n < 4; n++) bv[n] = bias2[cb2 * 128 + wc + n * 16 + ln];
#pragma unroll
    for (int m = 0; m < 4; m++)
#pragma unroll
        for (int q = 0; q < 4; q++) {
            const int t = wr + m * 16 + kg * 4 + q;
#pragma unroll
            for (int n = 0; n < 4; n++)
                ep[t * 128 + wc + n * 16 + ln] = (_Float16)(acc[m][n][q] + bv[n]);
        }
    __syncthreads();
    const int bg = b >> 4, kgs = (b >> 2) & 3, qs = b & 3;
    const size_t obase = (size_t)(bg * 128) * 8192 + (size_t)(cb2 * 2 * 64 + kgs * 16) * 16 + qs * 4;
#pragma unroll
    for (int j = 0; j < 16; j++) {
        const int wid = j * 256 + tid;       // 0..4095 = t2*32 + slb
        const int t2 = wid >> 5, slb = wid & 31;
        const half4 v = *(const half4*)&ep[t2 * 128 + slb * 4];
        *(half4*)&out[obase + (size_t)t2 * 8192 + (slb >> 4) * 1024 + (slb & 15) * 16] = v;
    }
}

// ---------------------------------------------------------------------------
// Scan v16 (R17 optimum): 32 blocks x 512 thr (8 waves, 2/SIMD). Wave w owns
// cols [w*64, w*64+64) with col = w*64 + ln*4 + nt; nt=0..2 as 48 AGPR frags
// (192 regs, "+a"-pinned), nt=3 from the 128KB LDS W tile. hb padded stride
// 136 (conflict-light). 2 lgkm-only barriers/step; rnn stores after barrier2.
// ---------------------------------------------------------------------------
__global__ __launch_bounds__(512, 2) void rnn_scan16(
    const _Float16* __restrict__ xps,     // packed scan-native x_proj
    const _Float16* __restrict__ wresA,   // AGPR frags
    const _Float16* __restrict__ wresL,   // LDS frags
    const int* __restrict__ term,         // [512][128] int32
    const float* __restrict__ h0,         // [512][512] f32
    float* dout) {
    __shared__ __align__(16) _Float16 hb[64 * HB_STRIDE];   // h, padded k8-major (17.4KB)
    __shared__ __align__(16) _Float16 wl[65536];            // W nt=3 tiles (128KB)
    __shared__ unsigned int term_lds[16][4];
    const int tid = threadIdx.x;
    const int bg = blockIdx.x;
    const int R0 = bg * 16;
    const int lane = tid & 63, w = tid >> 6;
    const int ln = lane & 15, kg = lane >> 4;
    _Float16* rnn = (_Float16*)dout;

    // ---- 48 AGPR frags (192 AGPRs); per-wave stride 48*512 = 24576 ----
    half8 wf[48];
    {
        const _Float16* wp = wresA + (size_t)w * 24576 + lane * 8;
#pragma unroll
        for (int f = 0; f < 48; f++) wf[f] = *(const half8*)(wp + (size_t)f * 512);
    }
#pragma unroll
    for (int f = 0; f < 48; f++) asm volatile("" : "+a"(wf[f]));

    // ---- stage LDS W tile (128KB linear) ----
    for (int u = 0; u < 16; u++) {
        const int o = (u * 512 + tid) * 8;
        *(half8*)&wl[o] = *(const half8*)(wresL + o);
    }
    // ---- h0 -> hb (f32 -> f16, padded k8-major) ----
    {
        const int r = tid >> 5, c0 = (tid & 31) * 16;
        const float* gh = h0 + (size_t)(R0 + r) * 512 + c0;
        half8 v0, v1;
#pragma unroll
        for (int i = 0; i < 8; i++) { v0[i] = (_Float16)gh[i]; v1[i] = (_Float16)gh[8 + i]; }
        const int kb = c0 >> 3;
        *(half8*)&hb[kb * HB_STRIDE + r * 8] = v0;
        *(half8*)&hb[(kb + 1) * HB_STRIDE + r * 8] = v1;
    }
    // ---- termination bitmasks ----
    if (tid < 64) {
        const int r = tid >> 2, word = tid & 3;
        unsigned int m = 0;
        for (int b2 = 0; b2 < 32; b2++)
            m |= (term[(R0 + r) * 128 + word * 32 + b2] ? 1u : 0u) << b2;
        term_lds[r][word] = m;
    }
    __syncthreads();   // startup barrier: full drain fine (once)

    const _Float16* xpt = xps + (size_t)(bg * 128) * 8192 + tid * 16;
    const _Float16* bl = &wl[(size_t)w * 8192];
    const int cb = w * 64 + ln * 4;                       // thread's 4-col base
    const int hoff = (cb >> 3) * HB_STRIDE + (cb & 7);    // hb write base (+row*8)
    unsigned int tmask[4];

#pragma unroll 1
    for (int t = 0; t < 128; ++t) {
        if ((t & 31) == 0) {
#pragma unroll
            for (int q = 0; q < 4; q++) tmask[q] = term_lds[kg * 4 + q][t >> 5];
        }
        // xp(t): 32B/thread, [q][nt] packed; lands during the MFMA phase
        const half8 xv0 = *(const half8*)(xpt);
        const half8 xv1 = *(const half8*)(xpt + 8);
        xpt += 8192;

        f32x4 acc[4];
#pragma unroll
        for (int n = 0; n < 4; n++) acc[n] = (f32x4)0.0f;

#pragma unroll
        for (int s = 0; s < 16; s++) {
            const half8 a = *(const half8*)&hb[(s * 4 + kg) * HB_STRIDE + ln * 8];
            acc[0] = __builtin_amdgcn_mfma_f32_16x16x32_f16(a, wf[s],      acc[0], 0, 0, 0);
            acc[1] = __builtin_amdgcn_mfma_f32_16x16x32_f16(a, wf[16 + s], acc[1], 0, 0, 0);
            acc[2] = __builtin_amdgcn_mfma_f32_16x16x32_f16(a, wf[32 + s], acc[2], 0, 0, 0);
            const half8 b4 = *(const half8*)(bl + s * 512 + lane * 8);
            acc[3] = __builtin_amdgcn_mfma_f32_16x16x32_f16(a, b4, acc[3], 0, 0, 0);
        }
        LDS_BARRIER();     // barrier1: h(t) reads done (lgkm only)

        // ---- tanh (rcp); masked h(t+1) -> hb as b64; keep unmasked half4s ----
        half4 hh4[4];
#pragma unroll
        for (int q = 0; q < 4; q++) {
            const bool dead = (tmask[q] >> (t & 31)) & 1;
            half4 v;
#pragma unroll
            for (int nt = 0; nt < 4; nt++) {
                const int u = q * 4 + nt;
                const float xval = (float)(u < 8 ? xv0[u] : xv1[u - 8]);
                const float pre = acc[nt][q] + xval;
                const float e = __expf(2.0f * pre);
                v[nt] = (_Float16)(1.0f - 2.0f * __builtin_amdgcn_rcpf(e + 1.0f));
            }
            hh4[q] = v;
            half4 mv = v;
            if (dead) { mv[0] = (_Float16)0; mv[1] = (_Float16)0; mv[2] = (_Float16)0; mv[3] = (_Float16)0; }
            *(half4*)&hb[hoff + (kg * 4 + q) * 8] = mv;
        }
        LDS_BARRIER();     // barrier2: h(t+1) visible (lgkm only)

        // ---- rnn_out stores: 4 x 8B, 16-lane 128B segments, no drain ----
#pragma unroll
        for (int q = 0; q < 4; q++)
            *(half4*)&rnn[((size_t)(R0 + kg * 4 + q) * 128 + t) * 512 + cb] = hh4[q];
    }

    // ---- h_final (masked h(128)) -> f32 at d_out + 65536*256 ----
    {
        const int r = tid >> 5, c0 = (tid & 31) * 16;
        const int kb = c0 >> 3;
        half8 v0 = *(const half8*)&hb[kb * HB_STRIDE + r * 8];
        half8 v1 = *(const half8*)&hb[(kb + 1) * HB_STRIDE + r * 8];
        float* gf = dout + (size_t)65536 * 256 + (size_t)(R0 + r) * 512 + c0;
#pragma unroll
        for (int i = 0; i < 8; i++) { gf[i] = (float)v0[i]; gf[8 + i] = (float)v1[i]; }
    }
}

// ---------------------------------------------------------------------------
// K3: logits[65536,256] (f32) = rnn_out(f16, in d_out) @ fc_w^T + fc_b
// ---------------------------------------------------------------------------
__global__ __launch_bounds__(512) void gemm_logits(const _Float16* Arnn,
                                                   const _Float16* __restrict__ Bw,
                                                   const float* __restrict__ biasv,
                                                   float* out) {
    __shared__ _Float16 As[128 * 32];
    __shared__ _Float16 Bs[256 * 32];
    const int tid = threadIdx.x;
    const int m0 = blockIdx.x * 128;
    const int lane = tid & 63, w = tid >> 6;
    const int wr = (w >> 2) * 64, wc = (w & 3) * 64;
    const int ln = lane & 15, kg = lane >> 4;

    f32x4 acc[4][4];
#pragma unroll
    for (int m = 0; m < 4; m++)
#pragma unroll
        for (int n = 0; n < 4; n++) acc[m][n] = (f32x4)0.0f;

    const int ar = tid >> 2, ac = (tid & 3) * 8;
    const int br = tid >> 1, bc = (tid & 1) * 16;

    for (int k0 = 0; k0 < 512; k0 += 32) {
        *(half8*)&As[ar * 32 + ac] = *(const half8*)(Arnn + (size_t)(m0 + ar) * 512 + k0 + ac);
        {
            const _Float16* gb = Bw + (size_t)br * 512 + k0 + bc;
            *(half8*)&Bs[br * 32 + bc] = *(const half8*)(gb);
            *(half8*)&Bs[br * 32 + bc + 8] = *(const half8*)(gb + 8);
        }
        __syncthreads();
        half8 af[4], bf[4];
#pragma unroll
        for (int m = 0; m < 4; m++) af[m] = *(const half8*)&As[(wr + m * 16 + ln) * 32 + kg * 8];
#pragma unroll
        for (int n = 0; n < 4; n++) bf[n] = *(const half8*)&Bs[(wc + n * 16 + ln) * 32 + kg * 8];
#pragma unroll
        for (int m = 0; m < 4; m++)
#pragma unroll
            for (int n = 0; n < 4; n++)
                acc[m][n] = __builtin_amdgcn_mfma_f32_16x16x32_f16(af[m], bf[n], acc[m][n], 0, 0, 0);
        __syncthreads();
    }
#pragma unroll
    for (int m = 0; m < 4; m++)
#pragma unroll
        for (int n = 0; n < 4; n++) {
            const int col = wc + n * 16 + ln;
            const float bv = biasv[col];
#pragma unroll
            for (int q = 0; q < 4; q++) {
                const int row = m0 + wr + m * 16 + kg * 4 + q;
                out[(size_t)row * 256 + col] = acc[m][n][q] + bv;
            }
        }
}

// ---------------------------------------------------------------------------
extern "C" void kernel_launch(void* const* d_in, const int* in_sizes, int n_in,
                              void* d_out, int out_size, void* d_ws, size_t ws_size,
                              hipStream_t stream) {
    const float* states = (const float*)d_in[0];
    const int*   term   = (const int*)d_in[1];
    const float* h0     = (const float*)d_in[2];
    const float* Wih    = (const float*)d_in[3];
    const float* Whh    = (const float*)d_in[4];
    const float* bih    = (const float*)d_in[5];
    const float* bhh    = (const float*)d_in[6];
    const float* fcw    = (const float*)d_in[7];
    const float* fcb    = (const float*)d_in[8];

    char* ws = (char*)d_ws;
    _Float16* xpw   = (_Float16*)(ws + XPW_OFF);
    _Float16* wih_h = (_Float16*)(ws + WIH_OFF);
    _Float16* fcw_h = (_Float16*)(ws + FCW_OFF);
    float*    bias2 = (float*)(ws + BIAS_OFF);
    _Float16* wresA = (_Float16*)(ws + WRESA_OFF);
    _Float16* wresL = (_Float16*)(ws + WRESL_OFF);

    conv_w<<<1024, 256, 0, stream>>>(Wih, Whh, fcw, bih, bhh, wih_h, fcw_h, bias2, wresA, wresL);
    gemm_xproj<<<2048, 256, 0, stream>>>(states, wih_h, bias2, xpw);
    rnn_scan16<<<32, 512, 0, stream>>>(xpw, wresA, wresL, term, h0, (float*)d_out);
    gemm_logits<<<512, 512, 0, stream>>>((const _Float16*)d_out, fcw_h, fcb, (float*)d_out);
}